// Round 13
// baseline (61.296 us; speedup 1.0000x reference)
//
#include <hip/hip_runtime.h>
#include <math.h>

#define B_  4
#define S_  2048
#define H_  16
#define DK_ 8
#define E_  128

typedef _Float16 f16x8  __attribute__((ext_vector_type(8)));
typedef __fp16   h2     __attribute__((ext_vector_type(2)));
typedef unsigned short us2 __attribute__((ext_vector_type(2)));
typedef float    f32x16 __attribute__((ext_vector_type(16)));
typedef int      i32x2  __attribute__((ext_vector_type(2)));

union U4  { unsigned u[4]; f16x8 v; uint4 q; };
union H2U { h2 h; us2 s; unsigned u; };

// log2(e)/sqrt(8): folds the 1/sqrt(dk) softmax scale and the exp->exp2 conversion
#define KSC 0.51006972f

static __device__ __forceinline__ float frcp(float x) {
#if __has_builtin(__builtin_amdgcn_rcpf)
    return __builtin_amdgcn_rcpf(x);
#else
    return 1.0f / x;
#endif
}

// ---------------------------------------------------------------------------
// Fused quantum projection + attention. r13: NO transcendentals in the main
// loop -- packed-f16 polynomial exp2, 2 scores per instruction, all ops on
// the full-rate VOP3P pipe. (Model from r4..r12: wall tracks VALU issue work
// at ~0.53 efficiency; v_exp_f32 wave64 is the dominant issue cost. r9's
// attempt failed on an inline-asm scheduling barrier; this version is pure C
// vector ops -> v_pk_add_f16 / v_pk_fma_f16 / v_pk_lshlrev_b16 / v_pk_add_u16.)
//   exp2(y), |y|<=4.6: t = y+1536 (f16 RNE -> round(y)+1536, bits low = j+512)
//   f = y-(t-1536) in [-.5,.5]; p = cubic(f) ~ 2^f (rel err ~8e-4)
//   sh = tbits<<10 (== j<<10 mod 2^16 per half); result = pbits + sh.
// ---------------------------------------------------------------------------
__global__ __launch_bounds__(512, 4)
void qattn_mfma(const float* __restrict__ x, const float* __restrict__ theta,
                float* __restrict__ out) {
    constexpr int VST = 2056;                       // V^T row stride (bank-spread, 16B aligned)
    __shared__ __align__(16) _Float16 smem[S_ * DK_ + 9 * VST];
    _Float16* Klds = smem;                          // [2048][8]
    _Float16* Vt   = smem + S_ * DK_;               // [9][VST]

    const int tid  = threadIdx.x;
    const int lane = tid & 63;
    const int wv   = tid >> 6;
    const int bh   = blockIdx.y;
    const int b    = bh >> 4;
    const int h    = bh & 15;

    // ---- stage cos(x+theta): K row-major + V^T (pairs of keys) ----
    {
        float th[DK_];
#pragma unroll
        for (int d = 0; d < DK_; ++d) th[d] = theta[d];

        const float* xp = x + ((size_t)b * S_) * E_ + h * DK_;
#pragma unroll
        for (int m = 0; m < 2; ++m) {
            const int s0 = tid * 4 + 2 * m;
            float4 a0 = *(const float4*)(xp + (size_t)s0 * E_);
            float4 a1 = *(const float4*)(xp + (size_t)s0 * E_ + 4);
            float4 b0 = *(const float4*)(xp + (size_t)(s0 + 1) * E_);
            float4 b1 = *(const float4*)(xp + (size_t)(s0 + 1) * E_ + 4);
            float ca[8], cb[8];
            ca[0]=__cosf(a0.x+th[0]); ca[1]=__cosf(a0.y+th[1]); ca[2]=__cosf(a0.z+th[2]); ca[3]=__cosf(a0.w+th[3]);
            ca[4]=__cosf(a1.x+th[4]); ca[5]=__cosf(a1.y+th[5]); ca[6]=__cosf(a1.z+th[6]); ca[7]=__cosf(a1.w+th[7]);
            cb[0]=__cosf(b0.x+th[0]); cb[1]=__cosf(b0.y+th[1]); cb[2]=__cosf(b0.z+th[2]); cb[3]=__cosf(b0.w+th[3]);
            cb[4]=__cosf(b1.x+th[4]); cb[5]=__cosf(b1.y+th[5]); cb[6]=__cosf(b1.z+th[6]); cb[7]=__cosf(b1.w+th[7]);

            H2U p0, p1, p2, p3;
            p0.h = __builtin_amdgcn_cvt_pkrtz(ca[0], ca[1]);
            p1.h = __builtin_amdgcn_cvt_pkrtz(ca[2], ca[3]);
            p2.h = __builtin_amdgcn_cvt_pkrtz(ca[4], ca[5]);
            p3.h = __builtin_amdgcn_cvt_pkrtz(ca[6], ca[7]);
            *(uint4*)&Klds[(size_t)s0 * DK_] = make_uint4(p0.u, p1.u, p2.u, p3.u);
            p0.h = __builtin_amdgcn_cvt_pkrtz(cb[0], cb[1]);
            p1.h = __builtin_amdgcn_cvt_pkrtz(cb[2], cb[3]);
            p2.h = __builtin_amdgcn_cvt_pkrtz(cb[4], cb[5]);
            p3.h = __builtin_amdgcn_cvt_pkrtz(cb[6], cb[7]);
            *(uint4*)&Klds[(size_t)(s0 + 1) * DK_] = make_uint4(p0.u, p1.u, p2.u, p3.u);

#pragma unroll
            for (int d = 0; d < DK_; ++d) {         // V^T: (key s0, s0+1) pair
                H2U tv; tv.h = __builtin_amdgcn_cvt_pkrtz(ca[d], cb[d]);
                *(unsigned*)&Vt[d * VST + s0] = tv.u;
            }
            *(unsigned*)&Vt[8 * VST + s0] = 0x3C003C00u;  // ones row -> denominator
        }
    }
    __syncthreads();

    // ---- per-wave 32 q-rows over all 2048 keys ----
    const int  qrow0 = blockIdx.x * 256 + wv * 32;
    const int  l31   = lane & 31;
    const int  hi    = lane >> 5;
    const bool lo32  = (lane < 32);

    f16x8 qf = {};                                  // Q^T B-frag: lanes>=32 zero (dims 8..15)
    if (lo32) {
        qf = *(const f16x8*)&Klds[(size_t)(qrow0 + l31) * DK_];
#pragma unroll
        for (int d = 0; d < DK_; ++d)               // fold softmax scale + log2e into Q
            qf[d] = qf[d] * (_Float16)KSC;
    }

    const f32x16 z16 = {};                          // constant zero C operand
    f32x16 accP = {}, accQ = {};                    // split O accumulators (by PV step)

    const int nc = (l31 <= 8) ? l31 : 8;            // clamp unused cols to ones row

    // pk-exp2 constants, hoisted (broadcast h2)
    const h2 kMag = {(__fp16)1536.0f, (__fp16)1536.0f};
    const h2 kC3  = {(__fp16)0.0554906f,  (__fp16)0.0554906f};
    const h2 kC2  = {(__fp16)0.2401597f,  (__fp16)0.2401597f};
    const h2 kC1  = {(__fp16)0.6931472f,  (__fp16)0.6931472f};
    const h2 kC0  = {(__fp16)1.0f,        (__fp16)1.0f};

    // hoisted byte-base pointers: every LDS read below is base + literal
    // immediate (kt*512 <= 32KB, kt*64+32 <= 4KB -- both fit ds offset:)
    const char* kbyte = (const char*)&Klds[(size_t)l31 * DK_];
    const char* vbyte = (const char*)&Vt[(size_t)nc * VST + hi * 8];

    // kf loads are unconditional: lanes>=32 duplicate their l31 partner's row;
    // their A-contribution hits qf's zeroed k=8..15 half -> 0.
#define LDK(T)    (*(const f16x8*)(kbyte + (size_t)(T) * 512))
#define LDV(T, S) (*(const f16x8*)(vbyte + (size_t)(T) * 64 + (S) * 32))

    // packed exp2 of a score pair: 1 cvt + 8 full-rate pk ops, no trans.
#define PKEXP2(LO, HI, OUT)                                                    \
    {                                                                          \
        H2U xx; xx.h = __builtin_amdgcn_cvt_pkrtz((LO), (HI));                 \
        H2U tt; tt.h = xx.h + kMag;             /* round(y)+1536 (RNE)  */     \
        h2  rr = tt.h - kMag;                   /* round(y)             */     \
        h2  ff = xx.h - rr;                     /* frac, [-0.5,0.5]     */     \
        h2  pp = ff * kC3 + kC2;                                               \
        pp = pp * ff + kC1;                                                    \
        pp = pp * ff + kC0;                     /* ~2^f, [0.70,1.42]    */     \
        H2U pu; pu.h = pp;                                                     \
        us2 sh = tt.s << 10;                    /* (j<<10) mod 2^16     */     \
        H2U rs; rs.s = pu.s + sh;               /* v_pk_add_u16         */     \
        OUT = rs.u;                                                            \
    }

    // exp/pack of tile T from SC; setprio(1) around the MFMA cluster.
#define PROC(SC, T, TN, REFILL)                                                \
    {                                                                          \
        unsigned X[4][2];                                                      \
        _Pragma("unroll")                                                      \
        for (int q = 0; q < 4; ++q) {                                          \
            PKEXP2(SC[4*q+0], SC[4*q+1], X[q][0])                              \
            PKEXP2(SC[4*q+2], SC[4*q+3], X[q][1])                              \
        }                                                                      \
        __builtin_amdgcn_s_setprio(1);                                         \
        if (REFILL)                                                            \
            SC = __builtin_amdgcn_mfma_f32_32x32x16_f16(LDK(TN), qf, z16,      \
                                                        0, 0, 0);              \
        {                                                                      \
            U4 pa;                                                             \
            _Pragma("unroll")                                                  \
            for (int i = 0; i < 2; ++i) {                                      \
                i32x2 r = __builtin_amdgcn_permlane32_swap(                    \
                    (int)X[0][i], (int)X[1][i], false, false);                 \
                pa.u[i]     = (unsigned)r[0];                                  \
                pa.u[2 + i] = (unsigned)r[1];                                  \
            }                                                                  \
            accP = __builtin_amdgcn_mfma_f32_32x32x16_f16(                     \
                pa.v, LDV(T, 0), accP, 0, 0, 0);                               \
        }                                                                      \
        {                                                                      \
            U4 pa;                                                             \
            _Pragma("unroll")                                                  \
            for (int i = 0; i < 2; ++i) {                                      \
                i32x2 r = __builtin_amdgcn_permlane32_swap(                    \
                    (int)X[2][i], (int)X[3][i], false, false);                 \
                pa.u[i]     = (unsigned)r[0];                                  \
                pa.u[2 + i] = (unsigned)r[1];                                  \
            }                                                                  \
            accQ = __builtin_amdgcn_mfma_f32_32x32x16_f16(                     \
                pa.v, LDV(T, 1), accQ, 0, 0, 0);                               \
        }                                                                      \
        __builtin_amdgcn_s_setprio(0);                                         \
    }

    f32x16 scA = __builtin_amdgcn_mfma_f32_32x32x16_f16(LDK(0), qf, z16, 0, 0, 0);
    f32x16 scB = __builtin_amdgcn_mfma_f32_32x32x16_f16(LDK(1), qf, z16, 0, 0, 0);

#pragma unroll 4
    for (int kt = 0; kt < 62; kt += 2) {
        PROC(scA, kt,     kt + 2, 1)
        PROC(scB, kt + 1, kt + 3, 1)
    }
    PROC(scA, 62, 0, 0)                             // tails: no refill
    PROC(scB, 63, 0, 0)
#undef PROC
#undef PKEXP2
#undef LDK
#undef LDV

    f32x16 accO;
#pragma unroll
    for (int i = 0; i < 16; ++i) accO[i] = accP[i] + accQ[i];

    // ---- epilogue: normalize by col-8 (ones column) and store ----
    const int n = l31;
    float* obase = out + ((size_t)(b * S_ + qrow0)) * E_ + h * DK_ + n;
#pragma unroll
    for (int i = 0; i < 16; ++i) {
        float den = __shfl(accO[i], (lane & 32) | 8, 64);
        float val = accO[i] * frcp(den);
        int row = (i & 3) + 8 * (i >> 2) + 4 * hi;
        if (n < DK_) obase[(size_t)row * E_] = val;
    }
}

// ---------------------------------------------------------------------------
// In-place output projection via f16 MFMA:  io[r][:] = io[r][:] @ Wc^T + bc.
// 128 blocks x 64 rows. A (64x128) and Wc (128x128) staged as f16 in 48KB LDS
// with 16B-chunk XOR swizzle; wave w owns row-group w&1, col-groups
// {2*(w>>1), 2*(w>>1)+1}; 8 K-steps of 32x32x16 mfma.
// ---------------------------------------------------------------------------
__global__ __launch_bounds__(256, 2)
void proj_mfma(const float* __restrict__ Wc, const float* __restrict__ bc,
               float* __restrict__ io) {
    __shared__ __align__(16) _Float16 As[64 * E_];   // 16KB
    __shared__ __align__(16) _Float16 Bs[E_ * E_];   // 32KB
    const int tid  = threadIdx.x;
    const int lane = tid & 63;
    const int wv   = tid >> 6;
    const int l31  = lane & 31;
    const int hi   = lane >> 5;
    const int r0   = blockIdx.x * 64;

    // stage A rows (io, fp32 -> f16) with chunk swizzle
    for (int i = tid; i < 64 * 16; i += 256) {
        int r = i >> 4, c = i & 15;
        const float* s = io + (size_t)(r0 + r) * E_ + c * 8;
        float4 a = *(const float4*)s;
        float4 b = *(const float4*)(s + 4);
        H2U p0, p1, p2, p3;
        p0.h = __builtin_amdgcn_cvt_pkrtz(a.x, a.y);
        p1.h = __builtin_amdgcn_cvt_pkrtz(a.z, a.w);
        p2.h = __builtin_amdgcn_cvt_pkrtz(b.x, b.y);
        p3.h = __builtin_amdgcn_cvt_pkrtz(b.z, b.w);
        *(uint4*)&As[r * E_ + ((c ^ (r & 7)) * 8)] = make_uint4(p0.u, p1.u, p2.u, p3.u);
    }
    // stage Wc (fp32 -> f16) with chunk swizzle
    for (int i = tid; i < E_ * 16; i += 256) {
        int r = i >> 4, c = i & 15;
        const float* s = Wc + (size_t)r * E_ + c * 8;
        float4 a = *(const float4*)s;
        float4 b = *(const float4*)(s + 4);
        H2U p0, p1, p2, p3;
        p0.h = __builtin_amdgcn_cvt_pkrtz(a.x, a.y);
        p1.h = __builtin_amdgcn_cvt_pkrtz(a.z, a.w);
        p2.h = __builtin_amdgcn_cvt_pkrtz(b.x, b.y);
        p3.h = __builtin_amdgcn_cvt_pkrtz(b.z, b.w);
        *(uint4*)&Bs[r * E_ + ((c ^ (r & 7)) * 8)] = make_uint4(p0.u, p1.u, p2.u, p3.u);
    }
    __syncthreads();

    const int rg = wv & 1;                // row-group: rows rg*32 + m
    const int cp = (wv >> 1) * 2;         // col-groups cp, cp+1

    f32x16 acc0 = {}, acc1 = {};
#pragma unroll
    for (int ks = 0; ks < 8; ++ks) {
        int ch = (ks * 2 + hi);
        f16x8 af  = *(const f16x8*)&As[(rg * 32 + l31) * E_ + ((ch ^ (l31 & 7)) * 8)];
        f16x8 bf0 = *(const f16x8*)&Bs[((cp + 0) * 32 + l31) * E_ + ((ch ^ (l31 & 7)) * 8)];
        f16x8 bf1 = *(const f16x8*)&Bs[((cp + 1) * 32 + l31) * E_ + ((ch ^ (l31 & 7)) * 8)];
        acc0 = __builtin_amdgcn_mfma_f32_32x32x16_f16(af, bf0, acc0, 0, 0, 0);
        acc1 = __builtin_amdgcn_mfma_f32_32x32x16_f16(af, bf1, acc1, 0, 0, 0);
    }

    const float b0 = bc[(cp + 0) * 32 + l31];
    const float b1 = bc[(cp + 1) * 32 + l31];
#pragma unroll
    for (int i = 0; i < 16; ++i) {
        int row = (i & 3) + 8 * (i >> 2) + 4 * hi;
        float* orow = io + (size_t)(r0 + rg * 32 + row) * E_;
        orow[(cp + 0) * 32 + l31] = acc0[i] + b0;
        orow[(cp + 1) * 32 + l31] = acc1[i] + b1;
    }
}

extern "C" void kernel_launch(void* const* d_in, const int* in_sizes, int n_in,
                              void* d_out, int out_size, void* d_ws, size_t ws_size,
                              hipStream_t stream) {
    const float* x     = (const float*)d_in[0];   // (4, 2048, 128)
    const float* theta = (const float*)d_in[1];   // (8,)
    const float* Wc    = (const float*)d_in[2];   // (128, 128)
    const float* bc    = (const float*)d_in[3];   // (128,)
    float* out = (float*)d_out;                   // (4, 2048, 128)

    qattn_mfma<<<dim3(S_ / 256, B_ * H_), 512, 0, stream>>>(x, theta, out);
    proj_mfma<<<dim3((B_ * S_) / 64), 256, 0, stream>>>(Wc, bc, out);
}

// Round 14
// 44.412 us; speedup vs baseline: 1.3802x; 1.3802x over previous
//
#include <hip/hip_runtime.h>
#include <math.h>

#define B_  4
#define S_  2048
#define H_  16
#define DK_ 8
#define E_  128

typedef _Float16 f16x8  __attribute__((ext_vector_type(8)));
typedef __fp16   h2     __attribute__((ext_vector_type(2)));
typedef float    f32x16 __attribute__((ext_vector_type(16)));

union U4  { unsigned u[4]; f16x8 v; uint4 q; };
union H2U { h2 h; unsigned u; };

// log2(e)/sqrt(8): folds the 1/sqrt(dk) softmax scale and the exp->exp2 conversion
#define KSC 0.51006972f

static __device__ __forceinline__ float fexp2(float x) {
#if __has_builtin(__builtin_amdgcn_exp2f)
    return __builtin_amdgcn_exp2f(x);          // bare v_exp_f32
#else
    return __builtin_exp2f(x);
#endif
}

static __device__ __forceinline__ float frcp(float x) {
#if __has_builtin(__builtin_amdgcn_rcpf)
    return __builtin_amdgcn_rcpf(x);
#else
    return 1.0f / x;
#endif
}

// ---------------------------------------------------------------------------
// Fused quantum projection + attention, MFMA path, 2-stage software pipeline.
// r14 change vs r12: keys within each 32-tile are PERMUTED (A-row r holds the
// key at position swap23(r) -- bits 2,3 of the row index swapped) so that the
// QK^T C-output register order IS the PV A-fragment order:
//   score in (reg,hi) sits at C-row r=(reg&3)+8*((reg>>2)&1)+4hi+16*(reg>>3);
//   PV A-frag element (s,e) of half hi multiplies V col s*16+hi*8+e = reg 8s+e;
//   key-position(r) = swap23(r) makes these coincide (sum over keys is
//   permutation-invariant). Result: the 8 permlane32_swap + movs per tile are
//   GONE -- exp'd scores pack in register order straight into the PV A-frags.
// Model (r4..r13): wall ~= VALU_busy/0.55; v_exp_f32 path is optimal (poly
// regressions r9/r13); only VALU-instruction removal moves the wall.
// ---------------------------------------------------------------------------
__global__ __launch_bounds__(512, 4)
void qattn_mfma(const float* __restrict__ x, const float* __restrict__ theta,
                float* __restrict__ out) {
    constexpr int VST = 2056;                       // V^T row stride (bank-spread, 16B aligned)
    __shared__ __align__(16) _Float16 smem[S_ * DK_ + 9 * VST];
    _Float16* Klds = smem;                          // [2048][8]
    _Float16* Vt   = smem + S_ * DK_;               // [9][VST]

    const int tid  = threadIdx.x;
    const int lane = tid & 63;
    const int wv   = tid >> 6;
    const int bh   = blockIdx.y;
    const int b    = bh >> 4;
    const int h    = bh & 15;

    // ---- stage cos(x+theta): K row-major + V^T (pairs of keys) ----
    {
        float th[DK_];
#pragma unroll
        for (int d = 0; d < DK_; ++d) th[d] = theta[d];

        const float* xp = x + ((size_t)b * S_) * E_ + h * DK_;
#pragma unroll
        for (int m = 0; m < 2; ++m) {
            const int s0 = tid * 4 + 2 * m;
            float4 a0 = *(const float4*)(xp + (size_t)s0 * E_);
            float4 a1 = *(const float4*)(xp + (size_t)s0 * E_ + 4);
            float4 b0 = *(const float4*)(xp + (size_t)(s0 + 1) * E_);
            float4 b1 = *(const float4*)(xp + (size_t)(s0 + 1) * E_ + 4);
            float ca[8], cb[8];
            ca[0]=__cosf(a0.x+th[0]); ca[1]=__cosf(a0.y+th[1]); ca[2]=__cosf(a0.z+th[2]); ca[3]=__cosf(a0.w+th[3]);
            ca[4]=__cosf(a1.x+th[4]); ca[5]=__cosf(a1.y+th[5]); ca[6]=__cosf(a1.z+th[6]); ca[7]=__cosf(a1.w+th[7]);
            cb[0]=__cosf(b0.x+th[0]); cb[1]=__cosf(b0.y+th[1]); cb[2]=__cosf(b0.z+th[2]); cb[3]=__cosf(b0.w+th[3]);
            cb[4]=__cosf(b1.x+th[4]); cb[5]=__cosf(b1.y+th[5]); cb[6]=__cosf(b1.z+th[6]); cb[7]=__cosf(b1.w+th[7]);

            H2U p0, p1, p2, p3;
            p0.h = __builtin_amdgcn_cvt_pkrtz(ca[0], ca[1]);
            p1.h = __builtin_amdgcn_cvt_pkrtz(ca[2], ca[3]);
            p2.h = __builtin_amdgcn_cvt_pkrtz(ca[4], ca[5]);
            p3.h = __builtin_amdgcn_cvt_pkrtz(ca[6], ca[7]);
            *(uint4*)&Klds[(size_t)s0 * DK_] = make_uint4(p0.u, p1.u, p2.u, p3.u);
            p0.h = __builtin_amdgcn_cvt_pkrtz(cb[0], cb[1]);
            p1.h = __builtin_amdgcn_cvt_pkrtz(cb[2], cb[3]);
            p2.h = __builtin_amdgcn_cvt_pkrtz(cb[4], cb[5]);
            p3.h = __builtin_amdgcn_cvt_pkrtz(cb[6], cb[7]);
            *(uint4*)&Klds[(size_t)(s0 + 1) * DK_] = make_uint4(p0.u, p1.u, p2.u, p3.u);

#pragma unroll
            for (int d = 0; d < DK_; ++d) {         // V^T: (key s0, s0+1) pair
                H2U tv; tv.h = __builtin_amdgcn_cvt_pkrtz(ca[d], cb[d]);
                *(unsigned*)&Vt[d * VST + s0] = tv.u;
            }
            *(unsigned*)&Vt[8 * VST + s0] = 0x3C003C00u;  // ones row -> denominator
        }
    }
    __syncthreads();

    // ---- per-wave 32 q-rows over all 2048 keys ----
    const int  qrow0 = blockIdx.x * 256 + wv * 32;
    const int  l31   = lane & 31;
    const int  hi    = lane >> 5;
    const bool lo32  = (lane < 32);

    f16x8 qf = {};                                  // Q^T B-frag: lanes>=32 zero (dims 8..15)
    if (lo32) {
        qf = *(const f16x8*)&Klds[(size_t)(qrow0 + l31) * DK_];
#pragma unroll
        for (int d = 0; d < DK_; ++d)               // fold softmax scale + log2e into Q
            qf[d] = qf[d] * (_Float16)KSC;
    }

    const f32x16 z16 = {};                          // constant zero C operand
    f32x16 accP = {}, accQ = {};                    // split O accumulators (by PV step)

    const int nc = (l31 <= 8) ? l31 : 8;            // clamp unused cols to ones row

    // key permutation: A-row l31 loads the key at position swap23(l31)
    // (bits 2<->3 swapped) -> QK output register order == PV A-frag order.
    const int rsw = (l31 & ~12) | ((l31 & 4) << 1) | ((l31 & 8) >> 1);

    // hoisted byte-base pointers: every LDS read below is base + literal
    // immediate (kt*512 <= 32KB, kt*64+32 <= 4KB -- both fit ds offset:)
    const char* kbyte = (const char*)&Klds[(size_t)rsw * DK_];
    const char* vbyte = (const char*)&Vt[(size_t)nc * VST + hi * 8];

    // kf loads are unconditional: lanes>=32 duplicate their l31 partner's row;
    // their A-contribution hits qf's zeroed k=8..15 half -> 0.
#define LDK(T)    (*(const f16x8*)(kbyte + (size_t)(T) * 512))
#define LDV(T, S) (*(const f16x8*)(vbyte + (size_t)(T) * 64 + (S) * 32))

    // exp/pack of tile T from SC (register-order pack, no cross-lane ops);
    // setprio(1) around the MFMA cluster (QK refill for TN + both PV mfmas).
#define PROC(SC, T, TN, REFILL)                                                \
    {                                                                          \
        U4 pa0, pa1;                                                           \
        _Pragma("unroll")                                                      \
        for (int i = 0; i < 4; ++i) {                                          \
            H2U plo, phi;                                                      \
            plo.h = __builtin_amdgcn_cvt_pkrtz(fexp2(SC[2*i+0]),               \
                                               fexp2(SC[2*i+1]));              \
            phi.h = __builtin_amdgcn_cvt_pkrtz(fexp2(SC[2*i+8]),               \
                                               fexp2(SC[2*i+9]));              \
            pa0.u[i] = plo.u;                                                  \
            pa1.u[i] = phi.u;                                                  \
        }                                                                      \
        __builtin_amdgcn_s_setprio(1);                                         \
        if (REFILL)                                                            \
            SC = __builtin_amdgcn_mfma_f32_32x32x16_f16(LDK(TN), qf, z16,      \
                                                        0, 0, 0);              \
        accP = __builtin_amdgcn_mfma_f32_32x32x16_f16(                         \
            pa0.v, LDV(T, 0), accP, 0, 0, 0);                                  \
        accQ = __builtin_amdgcn_mfma_f32_32x32x16_f16(                         \
            pa1.v, LDV(T, 1), accQ, 0, 0, 0);                                  \
        __builtin_amdgcn_s_setprio(0);                                         \
    }

    f32x16 scA = __builtin_amdgcn_mfma_f32_32x32x16_f16(LDK(0), qf, z16, 0, 0, 0);
    f32x16 scB = __builtin_amdgcn_mfma_f32_32x32x16_f16(LDK(1), qf, z16, 0, 0, 0);

#pragma unroll 4
    for (int kt = 0; kt < 62; kt += 2) {
        PROC(scA, kt,     kt + 2, 1)
        PROC(scB, kt + 1, kt + 3, 1)
    }
    PROC(scA, 62, 0, 0)                             // tails: no refill
    PROC(scB, 63, 0, 0)
#undef PROC
#undef LDK
#undef LDV

    f32x16 accO;
#pragma unroll
    for (int i = 0; i < 16; ++i) accO[i] = accP[i] + accQ[i];

    // ---- epilogue: normalize by col-8 (ones column) and store ----
    const int n = l31;
    float* obase = out + ((size_t)(b * S_ + qrow0)) * E_ + h * DK_ + n;
#pragma unroll
    for (int i = 0; i < 16; ++i) {
        float den = __shfl(accO[i], (lane & 32) | 8, 64);
        float val = accO[i] * frcp(den);
        int row = (i & 3) + 8 * (i >> 2) + 4 * hi;
        if (n < DK_) obase[(size_t)row * E_] = val;
    }
}

// ---------------------------------------------------------------------------
// In-place output projection via f16 MFMA:  io[r][:] = io[r][:] @ Wc^T + bc.
// 128 blocks x 64 rows. A (64x128) and Wc (128x128) staged as f16 in 48KB LDS
// with 16B-chunk XOR swizzle; wave w owns row-group w&1, col-groups
// {2*(w>>1), 2*(w>>1)+1}; 8 K-steps of 32x32x16 mfma.
// ---------------------------------------------------------------------------
__global__ __launch_bounds__(256, 2)
void proj_mfma(const float* __restrict__ Wc, const float* __restrict__ bc,
               float* __restrict__ io) {
    __shared__ __align__(16) _Float16 As[64 * E_];   // 16KB
    __shared__ __align__(16) _Float16 Bs[E_ * E_];   // 32KB
    const int tid  = threadIdx.x;
    const int lane = tid & 63;
    const int wv   = tid >> 6;
    const int l31  = lane & 31;
    const int hi   = lane >> 5;
    const int r0   = blockIdx.x * 64;

    // stage A rows (io, fp32 -> f16) with chunk swizzle
    for (int i = tid; i < 64 * 16; i += 256) {
        int r = i >> 4, c = i & 15;
        const float* s = io + (size_t)(r0 + r) * E_ + c * 8;
        float4 a = *(const float4*)s;
        float4 b = *(const float4*)(s + 4);
        H2U p0, p1, p2, p3;
        p0.h = __builtin_amdgcn_cvt_pkrtz(a.x, a.y);
        p1.h = __builtin_amdgcn_cvt_pkrtz(a.z, a.w);
        p2.h = __builtin_amdgcn_cvt_pkrtz(b.x, b.y);
        p3.h = __builtin_amdgcn_cvt_pkrtz(b.z, b.w);
        *(uint4*)&As[r * E_ + ((c ^ (r & 7)) * 8)] = make_uint4(p0.u, p1.u, p2.u, p3.u);
    }
    // stage Wc (fp32 -> f16) with chunk swizzle
    for (int i = tid; i < E_ * 16; i += 256) {
        int r = i >> 4, c = i & 15;
        const float* s = Wc + (size_t)r * E_ + c * 8;
        float4 a = *(const float4*)s;
        float4 b = *(const float4*)(s + 4);
        H2U p0, p1, p2, p3;
        p0.h = __builtin_amdgcn_cvt_pkrtz(a.x, a.y);
        p1.h = __builtin_amdgcn_cvt_pkrtz(a.z, a.w);
        p2.h = __builtin_amdgcn_cvt_pkrtz(b.x, b.y);
        p3.h = __builtin_amdgcn_cvt_pkrtz(b.z, b.w);
        *(uint4*)&Bs[r * E_ + ((c ^ (r & 7)) * 8)] = make_uint4(p0.u, p1.u, p2.u, p3.u);
    }
    __syncthreads();

    const int rg = wv & 1;                // row-group: rows rg*32 + m
    const int cp = (wv >> 1) * 2;         // col-groups cp, cp+1

    f32x16 acc0 = {}, acc1 = {};
#pragma unroll
    for (int ks = 0; ks < 8; ++ks) {
        int ch = (ks * 2 + hi);
        f16x8 af  = *(const f16x8*)&As[(rg * 32 + l31) * E_ + ((ch ^ (l31 & 7)) * 8)];
        f16x8 bf0 = *(const f16x8*)&Bs[((cp + 0) * 32 + l31) * E_ + ((ch ^ (l31 & 7)) * 8)];
        f16x8 bf1 = *(const f16x8*)&Bs[((cp + 1) * 32 + l31) * E_ + ((ch ^ (l31 & 7)) * 8)];
        acc0 = __builtin_amdgcn_mfma_f32_32x32x16_f16(af, bf0, acc0, 0, 0, 0);
        acc1 = __builtin_amdgcn_mfma_f32_32x32x16_f16(af, bf1, acc1, 0, 0, 0);
    }

    const float b0 = bc[(cp + 0) * 32 + l31];
    const float b1 = bc[(cp + 1) * 32 + l31];
#pragma unroll
    for (int i = 0; i < 16; ++i) {
        int row = (i & 3) + 8 * (i >> 2) + 4 * hi;
        float* orow = io + (size_t)(r0 + rg * 32 + row) * E_;
        orow[(cp + 0) * 32 + l31] = acc0[i] + b0;
        orow[(cp + 1) * 32 + l31] = acc1[i] + b1;
    }
}

extern "C" void kernel_launch(void* const* d_in, const int* in_sizes, int n_in,
                              void* d_out, int out_size, void* d_ws, size_t ws_size,
                              hipStream_t stream) {
    const float* x     = (const float*)d_in[0];   // (4, 2048, 128)
    const float* theta = (const float*)d_in[1];   // (8,)
    const float* Wc    = (const float*)d_in[2];   // (128, 128)
    const float* bc    = (const float*)d_in[3];   // (128,)
    float* out = (float*)d_out;                   // (4, 2048, 128)

    qattn_mfma<<<dim3(S_ / 256, B_ * H_), 512, 0, stream>>>(x, theta, out);
    proj_mfma<<<dim3((B_ * S_) / 64), 256, 0, stream>>>(Wc, bc, out);
}

// Round 15
// 43.676 us; speedup vs baseline: 1.4034x; 1.0169x over previous
//
#include <hip/hip_runtime.h>
#include <math.h>

#define B_  4
#define S_  2048
#define H_  16
#define DK_ 8
#define E_  128

typedef _Float16 f16x8  __attribute__((ext_vector_type(8)));
typedef __fp16   h2     __attribute__((ext_vector_type(2)));
typedef float    f32x16 __attribute__((ext_vector_type(16)));

union U4  { unsigned u[4]; f16x8 v; uint4 q; };
union H2U { h2 h; unsigned u; };

// log2(e)/sqrt(8): folds the 1/sqrt(dk) softmax scale and the exp->exp2 conversion
#define KSC 0.51006972f

static __device__ __forceinline__ float fexp2(float x) {
#if __has_builtin(__builtin_amdgcn_exp2f)
    return __builtin_amdgcn_exp2f(x);          // bare v_exp_f32
#else
    return __builtin_exp2f(x);
#endif
}

static __device__ __forceinline__ float frcp(float x) {
#if __has_builtin(__builtin_amdgcn_rcpf)
    return __builtin_amdgcn_rcpf(x);
#else
    return 1.0f / x;
#endif
}

// ---------------------------------------------------------------------------
// Fused quantum projection + attention (r14 structure, unchanged -- best
// known). Key permutation swap23 makes QK C-output register order == PV
// A-fragment order (no cross-lane ops); 2-stage score pipeline; split PV
// accumulators; trans-pipe exp (poly alternatives regressed, r9/r13).
// Model: wall/tile 371cyc = exp-trans-exec (~256, 69% util) || VALU issue
// (174) || MFMA (96). Symmetric exp-halving disproven by arithmetic
// (transpose+scatter/merge costs >= exp savings).
// ---------------------------------------------------------------------------
__global__ __launch_bounds__(512, 4)
void qattn_mfma(const float* __restrict__ x, const float* __restrict__ theta,
                float* __restrict__ out) {
    constexpr int VST = 2056;                       // V^T row stride (bank-spread, 16B aligned)
    __shared__ __align__(16) _Float16 smem[S_ * DK_ + 9 * VST];
    _Float16* Klds = smem;                          // [2048][8]
    _Float16* Vt   = smem + S_ * DK_;               // [9][VST]

    const int tid  = threadIdx.x;
    const int lane = tid & 63;
    const int wv   = tid >> 6;
    const int bh   = blockIdx.y;
    const int b    = bh >> 4;
    const int h    = bh & 15;

    // ---- stage cos(x+theta): K row-major + V^T (pairs of keys) ----
    {
        float th[DK_];
#pragma unroll
        for (int d = 0; d < DK_; ++d) th[d] = theta[d];

        const float* xp = x + ((size_t)b * S_) * E_ + h * DK_;
#pragma unroll
        for (int m = 0; m < 2; ++m) {
            const int s0 = tid * 4 + 2 * m;
            float4 a0 = *(const float4*)(xp + (size_t)s0 * E_);
            float4 a1 = *(const float4*)(xp + (size_t)s0 * E_ + 4);
            float4 b0 = *(const float4*)(xp + (size_t)(s0 + 1) * E_);
            float4 b1 = *(const float4*)(xp + (size_t)(s0 + 1) * E_ + 4);
            float ca[8], cb[8];
            ca[0]=__cosf(a0.x+th[0]); ca[1]=__cosf(a0.y+th[1]); ca[2]=__cosf(a0.z+th[2]); ca[3]=__cosf(a0.w+th[3]);
            ca[4]=__cosf(a1.x+th[4]); ca[5]=__cosf(a1.y+th[5]); ca[6]=__cosf(a1.z+th[6]); ca[7]=__cosf(a1.w+th[7]);
            cb[0]=__cosf(b0.x+th[0]); cb[1]=__cosf(b0.y+th[1]); cb[2]=__cosf(b0.z+th[2]); cb[3]=__cosf(b0.w+th[3]);
            cb[4]=__cosf(b1.x+th[4]); cb[5]=__cosf(b1.y+th[5]); cb[6]=__cosf(b1.z+th[6]); cb[7]=__cosf(b1.w+th[7]);

            H2U p0, p1, p2, p3;
            p0.h = __builtin_amdgcn_cvt_pkrtz(ca[0], ca[1]);
            p1.h = __builtin_amdgcn_cvt_pkrtz(ca[2], ca[3]);
            p2.h = __builtin_amdgcn_cvt_pkrtz(ca[4], ca[5]);
            p3.h = __builtin_amdgcn_cvt_pkrtz(ca[6], ca[7]);
            *(uint4*)&Klds[(size_t)s0 * DK_] = make_uint4(p0.u, p1.u, p2.u, p3.u);
            p0.h = __builtin_amdgcn_cvt_pkrtz(cb[0], cb[1]);
            p1.h = __builtin_amdgcn_cvt_pkrtz(cb[2], cb[3]);
            p2.h = __builtin_amdgcn_cvt_pkrtz(cb[4], cb[5]);
            p3.h = __builtin_amdgcn_cvt_pkrtz(cb[6], cb[7]);
            *(uint4*)&Klds[(size_t)(s0 + 1) * DK_] = make_uint4(p0.u, p1.u, p2.u, p3.u);

#pragma unroll
            for (int d = 0; d < DK_; ++d) {         // V^T: (key s0, s0+1) pair
                H2U tv; tv.h = __builtin_amdgcn_cvt_pkrtz(ca[d], cb[d]);
                *(unsigned*)&Vt[d * VST + s0] = tv.u;
            }
            *(unsigned*)&Vt[8 * VST + s0] = 0x3C003C00u;  // ones row -> denominator
        }
    }
    __syncthreads();

    // ---- per-wave 32 q-rows over all 2048 keys ----
    const int  qrow0 = blockIdx.x * 256 + wv * 32;
    const int  l31   = lane & 31;
    const int  hi    = lane >> 5;
    const bool lo32  = (lane < 32);

    f16x8 qf = {};                                  // Q^T B-frag: lanes>=32 zero (dims 8..15)
    if (lo32) {
        qf = *(const f16x8*)&Klds[(size_t)(qrow0 + l31) * DK_];
#pragma unroll
        for (int d = 0; d < DK_; ++d)               // fold softmax scale + log2e into Q
            qf[d] = qf[d] * (_Float16)KSC;
    }

    const f32x16 z16 = {};                          // constant zero C operand
    f32x16 accP = {}, accQ = {};                    // split O accumulators (by PV step)

    const int nc = (l31 <= 8) ? l31 : 8;            // clamp unused cols to ones row

    // key permutation: A-row l31 loads the key at position swap23(l31)
    // (bits 2<->3 swapped) -> QK output register order == PV A-frag order.
    const int rsw = (l31 & ~12) | ((l31 & 4) << 1) | ((l31 & 8) >> 1);

    const char* kbyte = (const char*)&Klds[(size_t)rsw * DK_];
    const char* vbyte = (const char*)&Vt[(size_t)nc * VST + hi * 8];

#define LDK(T)    (*(const f16x8*)(kbyte + (size_t)(T) * 512))
#define LDV(T, S) (*(const f16x8*)(vbyte + (size_t)(T) * 64 + (S) * 32))

#define PROC(SC, T, TN, REFILL)                                                \
    {                                                                          \
        U4 pa0, pa1;                                                           \
        _Pragma("unroll")                                                      \
        for (int i = 0; i < 4; ++i) {                                          \
            H2U plo, phi;                                                      \
            plo.h = __builtin_amdgcn_cvt_pkrtz(fexp2(SC[2*i+0]),               \
                                               fexp2(SC[2*i+1]));              \
            phi.h = __builtin_amdgcn_cvt_pkrtz(fexp2(SC[2*i+8]),               \
                                               fexp2(SC[2*i+9]));              \
            pa0.u[i] = plo.u;                                                  \
            pa1.u[i] = phi.u;                                                  \
        }                                                                      \
        __builtin_amdgcn_s_setprio(1);                                         \
        if (REFILL)                                                            \
            SC = __builtin_amdgcn_mfma_f32_32x32x16_f16(LDK(TN), qf, z16,      \
                                                        0, 0, 0);              \
        accP = __builtin_amdgcn_mfma_f32_32x32x16_f16(                         \
            pa0.v, LDV(T, 0), accP, 0, 0, 0);                                  \
        accQ = __builtin_amdgcn_mfma_f32_32x32x16_f16(                         \
            pa1.v, LDV(T, 1), accQ, 0, 0, 0);                                  \
        __builtin_amdgcn_s_setprio(0);                                         \
    }

    f32x16 scA = __builtin_amdgcn_mfma_f32_32x32x16_f16(LDK(0), qf, z16, 0, 0, 0);
    f32x16 scB = __builtin_amdgcn_mfma_f32_32x32x16_f16(LDK(1), qf, z16, 0, 0, 0);

#pragma unroll 4
    for (int kt = 0; kt < 62; kt += 2) {
        PROC(scA, kt,     kt + 2, 1)
        PROC(scB, kt + 1, kt + 3, 1)
    }
    PROC(scA, 62, 0, 0)                             // tails: no refill
    PROC(scB, 63, 0, 0)
#undef PROC
#undef LDK
#undef LDV

    f32x16 accO;
#pragma unroll
    for (int i = 0; i < 16; ++i) accO[i] = accP[i] + accQ[i];

    // ---- epilogue: normalize by col-8 (ones column) and store ----
    const int n = l31;
    float* obase = out + ((size_t)(b * S_ + qrow0)) * E_ + h * DK_ + n;
#pragma unroll
    for (int i = 0; i < 16; ++i) {
        float den = __shfl(accO[i], (lane & 32) | 8, 64);
        float val = accO[i] * frcp(den);
        int row = (i & 3) + 8 * (i >> 2) + 4 * hi;
        if (n < DK_) obase[(size_t)row * E_] = val;
    }
}

// ---------------------------------------------------------------------------
// In-place output projection via f16 MFMA:  io[r][:] = io[r][:] @ Wc^T + bc.
// r15: 256 blocks x 32 rows (was 128 x 64 -- only half the CUs were busy).
// A (32x128, 8KB) + Wc (128x128, 32KB) f16 in 40KB LDS -> 2+ blocks/CU.
// Wave w owns the single row-group, col-groups {w, w+4? no: 4 waves x
// 1 col-pair}: wave w takes col-groups {w}, {w+... 4 waves x 1 cp each
// covering cols w*32..w*32+31, each wave does all 8 K-steps for its cp.
// ---------------------------------------------------------------------------
__global__ __launch_bounds__(256, 2)
void proj_mfma(const float* __restrict__ Wc, const float* __restrict__ bc,
               float* __restrict__ io) {
    __shared__ __align__(16) _Float16 As[32 * E_];   // 8KB
    __shared__ __align__(16) _Float16 Bs[E_ * E_];   // 32KB
    const int tid  = threadIdx.x;
    const int lane = tid & 63;
    const int wv   = tid >> 6;
    const int l31  = lane & 31;
    const int hi   = lane >> 5;
    const int r0   = blockIdx.x * 32;

    // stage A rows (io, fp32 -> f16) with chunk swizzle
    for (int i = tid; i < 32 * 16; i += 256) {
        int r = i >> 4, c = i & 15;
        const float* s = io + (size_t)(r0 + r) * E_ + c * 8;
        float4 a = *(const float4*)s;
        float4 b = *(const float4*)(s + 4);
        H2U p0, p1, p2, p3;
        p0.h = __builtin_amdgcn_cvt_pkrtz(a.x, a.y);
        p1.h = __builtin_amdgcn_cvt_pkrtz(a.z, a.w);
        p2.h = __builtin_amdgcn_cvt_pkrtz(b.x, b.y);
        p3.h = __builtin_amdgcn_cvt_pkrtz(b.z, b.w);
        *(uint4*)&As[r * E_ + ((c ^ (r & 7)) * 8)] = make_uint4(p0.u, p1.u, p2.u, p3.u);
    }
    // stage Wc (fp32 -> f16) with chunk swizzle
    for (int i = tid; i < E_ * 16; i += 256) {
        int r = i >> 4, c = i & 15;
        const float* s = Wc + (size_t)r * E_ + c * 8;
        float4 a = *(const float4*)s;
        float4 b = *(const float4*)(s + 4);
        H2U p0, p1, p2, p3;
        p0.h = __builtin_amdgcn_cvt_pkrtz(a.x, a.y);
        p1.h = __builtin_amdgcn_cvt_pkrtz(a.z, a.w);
        p2.h = __builtin_amdgcn_cvt_pkrtz(b.x, b.y);
        p3.h = __builtin_amdgcn_cvt_pkrtz(b.z, b.w);
        *(uint4*)&Bs[r * E_ + ((c ^ (r & 7)) * 8)] = make_uint4(p0.u, p1.u, p2.u, p3.u);
    }
    __syncthreads();

    const int cp = wv;                    // wave w -> output cols w*32..w*32+31

    f32x16 acc = {};
#pragma unroll
    for (int ks = 0; ks < 8; ++ks) {
        int ch = (ks * 2 + hi);
        f16x8 af = *(const f16x8*)&As[l31 * E_ + ((ch ^ (l31 & 7)) * 8)];
        f16x8 bf = *(const f16x8*)&Bs[(cp * 32 + l31) * E_ + ((ch ^ (l31 & 7)) * 8)];
        acc = __builtin_amdgcn_mfma_f32_32x32x16_f16(af, bf, acc, 0, 0, 0);
    }

    const float bias = bc[cp * 32 + l31];
    __syncthreads();                      // all in-place reads of io done
#pragma unroll
    for (int i = 0; i < 16; ++i) {
        int row = (i & 3) + 8 * (i >> 2) + 4 * hi;
        io[(size_t)(r0 + row) * E_ + cp * 32 + l31] = acc[i] + bias;
    }
}

extern "C" void kernel_launch(void* const* d_in, const int* in_sizes, int n_in,
                              void* d_out, int out_size, void* d_ws, size_t ws_size,
                              hipStream_t stream) {
    const float* x     = (const float*)d_in[0];   // (4, 2048, 128)
    const float* theta = (const float*)d_in[1];   // (8,)
    const float* Wc    = (const float*)d_in[2];   // (128, 128)
    const float* bc    = (const float*)d_in[3];   // (128,)
    float* out = (float*)d_out;                   // (4, 2048, 128)

    qattn_mfma<<<dim3(S_ / 256, B_ * H_), 512, 0, stream>>>(x, theta, out);
    proj_mfma<<<dim3((B_ * S_) / 32), 256, 0, stream>>>(Wc, bc, out);
}